// Round 1
// baseline (7177.772 us; speedup 1.0000x reference)
//
#include <hip/hip_runtime.h>

#define NCOLS 8

// Zero the output (harness poisons d_out once and never re-zeroes between
// timed replays; we accumulate with atomics, so we must clear every call).
__global__ __launch_bounds__(256) void lap_zero_kernel(float4* __restrict__ out, int n4) {
    int i = blockIdx.x * blockDim.x + threadIdx.x;
    if (i < n4) out[i] = make_float4(0.f, 0.f, 0.f, 0.f);
}

// One thread per nnz entry: gather field row (2x float4), scale, 8 atomic adds.
// Index width (int32 vs int64) is auto-detected: all index values are < 2^20,
// so if the buffer is int64, every high 32-bit word is zero. int32 data has
// random values in [0, 1e6) at odd word positions -> P(16 zeros) ~ 1e-96.
__global__ __launch_bounds__(256) void lap_spmm_atomic(
    const float* __restrict__ vals,
    const void*  __restrict__ rowp,
    const void*  __restrict__ colp,
    const float* __restrict__ field,
    float* __restrict__ out,
    int nnz)
{
    __shared__ int s_is64;
    if (threadIdx.x == 0) {
        const unsigned* rw = (const unsigned*)rowp;
        int is64 = 1;
        #pragma unroll
        for (int k = 0; k < 16; ++k) is64 &= (rw[2 * k + 1] == 0u) ? 1 : 0;
        s_is64 = is64;
    }
    __syncthreads();
    const int is64 = s_is64;

    int i = blockIdx.x * blockDim.x + threadIdx.x;
    if (i >= nnz) return;

    float v = vals[i];
    int r, c;
    if (is64) {
        r = (int)((const long long*)rowp)[i];
        c = (int)((const long long*)colp)[i];
    } else {
        r = ((const int*)rowp)[i];
        c = ((const int*)colp)[i];
    }

    const float4* f = (const float4*)(field + (size_t)c * NCOLS);
    float4 f0 = f[0];
    float4 f1 = f[1];

    float* o = out + (size_t)r * NCOLS;
    unsafeAtomicAdd(o + 0, v * f0.x);
    unsafeAtomicAdd(o + 1, v * f0.y);
    unsafeAtomicAdd(o + 2, v * f0.z);
    unsafeAtomicAdd(o + 3, v * f0.w);
    unsafeAtomicAdd(o + 4, v * f1.x);
    unsafeAtomicAdd(o + 5, v * f1.y);
    unsafeAtomicAdd(o + 6, v * f1.z);
    unsafeAtomicAdd(o + 7, v * f1.w);
}

extern "C" void kernel_launch(void* const* d_in, const int* in_sizes, int n_in,
                              void* d_out, int out_size, void* d_ws, size_t ws_size,
                              hipStream_t stream) {
    const float* field = (const float*)d_in[0];
    const float* vals  = (const float*)d_in[1];
    const void*  rowp  = d_in[2];
    const void*  colp  = d_in[3];
    float* out = (float*)d_out;

    const int nnz = in_sizes[1];

    // Zero output first (same stream -> ordered before the scatter kernel).
    const int n4 = out_size / 4;
    lap_zero_kernel<<<(n4 + 255) / 256, 256, 0, stream>>>((float4*)out, n4);

    lap_spmm_atomic<<<(nnz + 255) / 256, 256, 0, stream>>>(
        vals, rowp, colp, field, out, nnz);
}

// Round 2
// 1283.403 us; speedup vs baseline: 5.5928x; 5.5928x over previous
//
#include <hip/hip_runtime.h>

#define NCOLS 8
#define BLOCK 256
#define NB    512        // streaming blocks for hist/scatter (contiguous chunks)
#define NBKT  1024       // row buckets
#define RPB   1024       // rows per bucket (row >> 10)

// ---------- index-width autodetect (int32 vs int64 COO indices) ----------
// All index values < 2^20, so int64 data has zero high words. P(false pos) ~ 1e-96.
__device__ __forceinline__ int detect_is64(const void* p, int* s_flag) {
    if (threadIdx.x == 0) {
        const unsigned* w = (const unsigned*)p;
        int is64 = 1;
        #pragma unroll
        for (int k = 0; k < 16; ++k) is64 &= (w[2 * k + 1] == 0u) ? 1 : 0;
        *s_flag = is64;
    }
    __syncthreads();
    return *s_flag;
}

__device__ __forceinline__ int load_idx(const void* p, int i, int is64) {
    return is64 ? (int)((const long long*)p)[i] : ((const int*)p)[i];
}

// ---------- k0: zero the global bucket counts (must happen every call) ----------
__global__ __launch_bounds__(BLOCK) void k_zero_counts(unsigned* __restrict__ counts) {
    int i = blockIdx.x * BLOCK + threadIdx.x;
    if (i < NBKT) counts[i] = 0u;
}

// ---------- k1: per-block histogram of row buckets ----------
__global__ __launch_bounds__(BLOCK) void k_hist(
    const void* __restrict__ rowp, int nnz, int chunk,
    unsigned* __restrict__ counts, unsigned* __restrict__ blockhist)
{
    __shared__ unsigned h[NBKT];
    __shared__ int s_flag;
    const int is64 = detect_is64(rowp, &s_flag);
    for (int b = threadIdx.x; b < NBKT; b += BLOCK) h[b] = 0u;
    __syncthreads();

    const int beg = blockIdx.x * chunk;
    const int end = min(nnz, beg + chunk);
    for (int i = beg + threadIdx.x; i < end; i += BLOCK) {
        int r = load_idx(rowp, i, is64);
        atomicAdd(&h[r >> 10], 1u);
    }
    __syncthreads();
    for (int b = threadIdx.x; b < NBKT; b += BLOCK) {
        unsigned c = h[b];
        blockhist[(size_t)blockIdx.x * NBKT + b] = c;
        if (c) atomicAdd(&counts[b], c);
    }
}

// ---------- k2: exclusive scan over 1024 bucket counts (single block) ----------
__global__ __launch_bounds__(NBKT) void k_scan(
    const unsigned* __restrict__ counts,
    unsigned* __restrict__ base, unsigned* __restrict__ cursor)
{
    __shared__ unsigned s[NBKT];
    const int t = threadIdx.x;
    const unsigned c = counts[t];
    s[t] = c;
    __syncthreads();
    for (int off = 1; off < NBKT; off <<= 1) {
        unsigned v = (t >= off) ? s[t - off] : 0u;
        __syncthreads();
        s[t] += v;
        __syncthreads();
    }
    const unsigned excl = s[t] - c;   // exclusive prefix
    base[t] = excl;
    cursor[t] = excl;
    if (t == NBKT - 1) base[NBKT] = s[t];   // total == nnz
}

// ---------- k3: scatter records into bucket-sorted order ----------
// record = (localrow<<20 | col, bits(val)), 8 bytes
__global__ __launch_bounds__(BLOCK) void k_scatter(
    const float* __restrict__ vals, const void* __restrict__ rowp,
    const void* __restrict__ colp, int nnz, int chunk,
    const unsigned* __restrict__ blockhist, unsigned* __restrict__ cursor,
    uint2* __restrict__ records)
{
    __shared__ unsigned lcur[NBKT];
    __shared__ int s_flag;
    const int is64 = detect_is64(rowp, &s_flag);

    // reserve per-(block,bucket) contiguous ranges
    for (int b = threadIdx.x; b < NBKT; b += BLOCK) {
        unsigned h = blockhist[(size_t)blockIdx.x * NBKT + b];
        lcur[b] = h ? atomicAdd(&cursor[b], h) : 0u;
    }
    __syncthreads();

    const int beg = blockIdx.x * chunk;
    const int end = min(nnz, beg + chunk);
    for (int i = beg + threadIdx.x; i < end; i += BLOCK) {
        int r = load_idx(rowp, i, is64);
        int c = load_idx(colp, i, is64);
        float v = vals[i];
        unsigned pos = atomicAdd(&lcur[r >> 10], 1u);
        records[pos] = make_uint2(((unsigned)(r & (RPB - 1)) << 20) | (unsigned)c,
                                  __float_as_uint(v));
    }
}

// ---------- k4: per-bucket gather + LDS-privatized accumulate + coalesced store ----------
__global__ __launch_bounds__(BLOCK) void k_accum(
    const uint2* __restrict__ records, const unsigned* __restrict__ base,
    const float* __restrict__ field, float* __restrict__ out, int n)
{
    // transposed layout acc[j][r]: bank = r & 31 -> random rows spread banks
    __shared__ float acc[NCOLS * RPB];   // 32 KB
    for (int i = threadIdx.x; i < NCOLS * RPB; i += BLOCK) acc[i] = 0.f;
    __syncthreads();

    const int b = blockIdx.x;
    const unsigned beg = base[b], end = base[b + 1];
    for (unsigned i = beg + threadIdx.x; i < end; i += BLOCK) {
        uint2 rec = records[i];
        unsigned col = rec.x & 0xFFFFFu;
        unsigned lr  = rec.x >> 20;
        float v = __uint_as_float(rec.y);
        const float4* f = (const float4*)(field + (size_t)col * NCOLS);
        float4 f0 = f[0];
        float4 f1 = f[1];
        atomicAdd(&acc[0 * RPB + lr], v * f0.x);
        atomicAdd(&acc[1 * RPB + lr], v * f0.y);
        atomicAdd(&acc[2 * RPB + lr], v * f0.z);
        atomicAdd(&acc[3 * RPB + lr], v * f0.w);
        atomicAdd(&acc[4 * RPB + lr], v * f1.x);
        atomicAdd(&acc[5 * RPB + lr], v * f1.y);
        atomicAdd(&acc[6 * RPB + lr], v * f1.z);
        atomicAdd(&acc[7 * RPB + lr], v * f1.w);
    }
    __syncthreads();

    const size_t row0 = (size_t)b * RPB;
    for (int t = threadIdx.x; t < NCOLS * RPB; t += BLOCK) {
        int r = t >> 3, j = t & 7;
        size_t gr = row0 + (size_t)r;
        if (gr < (size_t)n) out[gr * NCOLS + j] = acc[j * RPB + r];
    }
}

// ---------- fallback (round-1 atomic path) if workspace is too small ----------
__global__ __launch_bounds__(BLOCK) void lap_zero_kernel(float4* __restrict__ out, int n4) {
    int i = blockIdx.x * BLOCK + threadIdx.x;
    if (i < n4) out[i] = make_float4(0.f, 0.f, 0.f, 0.f);
}

__global__ __launch_bounds__(BLOCK) void lap_spmm_atomic(
    const float* __restrict__ vals, const void* __restrict__ rowp,
    const void* __restrict__ colp, const float* __restrict__ field,
    float* __restrict__ out, int nnz)
{
    __shared__ int s_flag;
    const int is64 = detect_is64(rowp, &s_flag);
    int i = blockIdx.x * BLOCK + threadIdx.x;
    if (i >= nnz) return;
    float v = vals[i];
    int r = load_idx(rowp, i, is64);
    int c = load_idx(colp, i, is64);
    const float4* f = (const float4*)(field + (size_t)c * NCOLS);
    float4 f0 = f[0], f1 = f[1];
    float* o = out + (size_t)r * NCOLS;
    unsafeAtomicAdd(o + 0, v * f0.x);
    unsafeAtomicAdd(o + 1, v * f0.y);
    unsafeAtomicAdd(o + 2, v * f0.z);
    unsafeAtomicAdd(o + 3, v * f0.w);
    unsafeAtomicAdd(o + 4, v * f1.x);
    unsafeAtomicAdd(o + 5, v * f1.y);
    unsafeAtomicAdd(o + 6, v * f1.z);
    unsafeAtomicAdd(o + 7, v * f1.w);
}

extern "C" void kernel_launch(void* const* d_in, const int* in_sizes, int n_in,
                              void* d_out, int out_size, void* d_ws, size_t ws_size,
                              hipStream_t stream) {
    const float* field = (const float*)d_in[0];
    const float* vals  = (const float*)d_in[1];
    const void*  rowp  = d_in[2];
    const void*  colp  = d_in[3];
    float* out = (float*)d_out;

    const int nnz = in_sizes[1];
    const int n   = out_size / NCOLS;

    // workspace layout (bytes)
    const size_t off_counts    = 0;                        // 1024 u32
    const size_t off_base      = 8192;                     // 1025 u32
    const size_t off_cursor    = 16384;                    // 1024 u32
    const size_t off_blockhist = 24576;                    // NB*NBKT u32 = 2 MB
    const size_t off_records   = off_blockhist + (size_t)NB * NBKT * 4;
    const size_t need = off_records + (size_t)nnz * 8;

    if (ws_size < need || n > NBKT * RPB) {
        // fallback: direct atomic scatter
        const int n4 = out_size / 4;
        lap_zero_kernel<<<(n4 + BLOCK - 1) / BLOCK, BLOCK, 0, stream>>>((float4*)out, n4);
        lap_spmm_atomic<<<(nnz + BLOCK - 1) / BLOCK, BLOCK, 0, stream>>>(
            vals, rowp, colp, field, out, nnz);
        return;
    }

    char* ws = (char*)d_ws;
    unsigned* counts    = (unsigned*)(ws + off_counts);
    unsigned* base      = (unsigned*)(ws + off_base);
    unsigned* cursor    = (unsigned*)(ws + off_cursor);
    unsigned* blockhist = (unsigned*)(ws + off_blockhist);
    uint2*    records   = (uint2*)   (ws + off_records);

    const int chunk = (nnz + NB - 1) / NB;

    k_zero_counts<<<(NBKT + BLOCK - 1) / BLOCK, BLOCK, 0, stream>>>(counts);
    k_hist<<<NB, BLOCK, 0, stream>>>(rowp, nnz, chunk, counts, blockhist);
    k_scan<<<1, NBKT, 0, stream>>>(counts, base, cursor);
    k_scatter<<<NB, BLOCK, 0, stream>>>(vals, rowp, colp, nnz, chunk,
                                        blockhist, cursor, records);
    k_accum<<<NBKT, BLOCK, 0, stream>>>(records, base, field, out, n);
}